// Round 10
// baseline (166.837 us; speedup 1.0000x reference)
//
#include <hip/hip_runtime.h>
#include <hip/hip_bf16.h>

// B=32 L=1024 D=128 H=128 W=9 F=137. Output f32 (32,1024,128).
// Split design: prep -> fg (GEMM) -> wt (softmax) -> out (fused GEMM).
// ws: W12Frag bf16[64t][64][8]   @0        (64KB)
//     CwFrag  bf16[288t][64][8]  @65536    (288KB)
//     wtT     f32[9][32768]      @360448   (1.18MB)
//     FG      bf16[32768][256]   @1540096  (16.78MB)  [row][part*128+p], p=(h&15)*8+(h>>4)
// Fragment order (16x16x32 B-frag): tile=(nTile,kk); lane l holds n=nTile*16+(l&15),
// k=kk*32+(l>>4)*8..+8 — wave bf16x8 load = 1KB coalesced.
// FG stores K*f and K*g (TANHK-prescaled, bf16 — proven R6 numerics).
// tanh(x)=1-2*rcp(1+exp2(K*x)), K=2*log2(e); Sum_h vw const cancels in softmax.

typedef __attribute__((ext_vector_type(8))) short bf16x8;
typedef __attribute__((ext_vector_type(4))) float f32x4;

#define LL 1024
#define TANHK 2.885390081777927f

__device__ __forceinline__ unsigned short f2bf(float f) {
  unsigned int u = __float_as_uint(f);
  u = u + 0x7FFFu + ((u >> 16) & 1u);   // RNE
  return (unsigned short)(u >> 16);
}
__device__ __forceinline__ float bf2f(unsigned short us) {
  return __uint_as_float(((unsigned int)us) << 16);
}
__device__ __forceinline__ unsigned cvt_pk_bf16(float lo, float hi) {
  unsigned r;
  asm("v_cvt_pk_bf16_f32 %0, %1, %2" : "=v"(r) : "v"(lo), "v"(hi));
  return r;
}

// ---------- prep: fragment-ordered bf16 weight copies (proven R6) ----------
__global__ __launch_bounds__(256) void prep_kernel(
    const float* __restrict__ w1, const float* __restrict__ w2,
    const float* __restrict__ cnn,
    unsigned short* __restrict__ W12Frag, unsigned short* __restrict__ CwFrag) {
  int gid = blockIdx.x * 256 + threadIdx.x;
  if (blockIdx.x < 128) {            // 32768: W12Frag
    int d = gid >> 8, n = gid & 255;
    float v = (n < 128) ? w1[d * 128 + n] : w2[d * 128 + (n - 128)];
    int tile = (n >> 4) * 4 + (d >> 5);
    int lane = ((d >> 3) & 3) * 16 + (n & 15);
    W12Frag[(tile * 64 + lane) * 8 + (d & 7)] = f2bf(v);
  } else {                           // 147456: CwFrag
    int idx = gid - 32768;
    int h = idx & 127;
    int wd = idx >> 7;
    int w = wd >> 7, d = wd & 127;
    float v = cnn[(w * 137 + d) * 128 + h];
    int tile = (w * 8 + (h >> 4)) * 4 + (d >> 5);
    int lane = ((d >> 3) & 3) * 16 + (h & 15);
    CwFrag[(tile * 64 + lane) * 8 + (d & 7)] = f2bf(v);
  }
}

// ---------- K1: FG = K*(emb @ [w1d|w2d]); barrier-free, LDS-free ----------
__global__ __launch_bounds__(64, 8) void fg_kernel(
    const float* __restrict__ emb, const unsigned short* __restrict__ W12Frag,
    unsigned short* __restrict__ FG) {
  int bid = blockIdx.x;              // 2048 blocks: (row32, part)
  int part = bid & 1;
  int r0 = (bid >> 1) << 5;
  int lane = threadIdx.x;
  int l15 = lane & 15, l4 = lane >> 4;
  const bf16x8* Wf = (const bf16x8*)W12Frag;

  f32x4 acc[2][8];
  #pragma unroll
  for (int m = 0; m < 2; ++m)
    #pragma unroll
    for (int nn = 0; nn < 8; ++nn) acc[m][nn] = (f32x4){0.f, 0.f, 0.f, 0.f};

  #pragma unroll
  for (int kk = 0; kk < 4; ++kk) {
    bf16x8 aF[2];
    #pragma unroll
    for (int m = 0; m < 2; ++m) {
      const float4* src = (const float4*)(emb +
          (size_t)(r0 + m * 16 + l15) * 128 + kk * 32 + l4 * 8);
      float4 x0 = src[0], x1 = src[1];
      uint4 v;
      v.x = cvt_pk_bf16(x0.x, x0.y);
      v.y = cvt_pk_bf16(x0.z, x0.w);
      v.z = cvt_pk_bf16(x1.x, x1.y);
      v.w = cvt_pk_bf16(x1.z, x1.w);
      aF[m] = *(bf16x8*)&v;
    }
    #pragma unroll
    for (int nn = 0; nn < 8; ++nn) {
      bf16x8 bF = Wf[((part * 8 + nn) * 4 + kk) * 64 + lane];
      #pragma unroll
      for (int m = 0; m < 2; ++m)
        acc[m][nn] = __builtin_amdgcn_mfma_f32_16x16x32_bf16(aF[m], bF, acc[m][nn], 0, 0, 0);
    }
  }
  // write prescaled, permuted p = l15*8 + nn (h = nn*16 + l15)
  #pragma unroll
  for (int m = 0; m < 2; ++m)
    #pragma unroll
    for (int j = 0; j < 4; ++j) {
      int row = r0 + m * 16 + l4 * 4 + j;
      uint4 v;
      v.x = cvt_pk_bf16(TANHK * acc[m][0][j], TANHK * acc[m][1][j]);
      v.y = cvt_pk_bf16(TANHK * acc[m][2][j], TANHK * acc[m][3][j]);
      v.z = cvt_pk_bf16(TANHK * acc[m][4][j], TANHK * acc[m][5][j]);
      v.w = cvt_pk_bf16(TANHK * acc[m][6][j], TANHK * acc[m][7][j]);
      *(uint4*)(FG + (size_t)row * 256 + part * 128 + l15 * 8) = v;
    }
}

// ---------- K2: scores + softmax -> wtT[9][32768] ----------
__global__ __launch_bounds__(256, 4) void wt_kernel(
    const unsigned short* __restrict__ FG,
    const float* __restrict__ w1, const float* __restrict__ w1b,
    const float* __restrict__ w2, const float* __restrict__ w2b,
    const float* __restrict__ vw, float* __restrict__ wtT) {
  __shared__ float pwP[1152];
  __shared__ float vwP[128];
  int tid = threadIdx.x;
  #pragma unroll
  for (int s = 0; s < 5; ++s) {
    int i = tid + s * 256;
    if (i < 1152) {
      int w = i >> 7, p = i & 127;
      int h = ((p & 7) << 4) + (p >> 3);
      pwP[i] = TANHK * (w2[(128 + w) * 128 + h] + w2b[h] +
                        w1[132 * 128 + h] + w1b[h]);
    } else if (i < 1280) {
      int p = i - 1152;
      int h = ((p & 7) << 4) + (p >> 3);
      vwP[p] = vw[h];
    }
  }
  __syncthreads();

  int r0 = blockIdx.x << 5;          // 1024 blocks x 32 rows
  int gb = r0 & ~1023;               // batch base row
  int lc0 = r0 & 1023;
  int lane = tid & 63, wid = tid >> 6;
  int l15 = lane & 15, l4 = lane >> 4;
  int u8 = l15 * 8;
  int rbase = (wid & 1) << 4;
  f32x4 vr0 = *(const f32x4*)(vwP + u8);
  f32x4 vr1 = *(const f32x4*)(vwP + u8 + 4);
  const bf16x8 gz = {0, 0, 0, 0, 0, 0, 0, 0};

#define DO_SCORE(J)                                                            \
  {                                                                            \
    int rl = rbase + l4 * 4 + (J);                                             \
    int row = r0 + rl, lcol = lc0 + rl;                                        \
    bf16x8 fraw = *(const bf16x8*)(FG + (size_t)row * 256 + u8);               \
    float sc[9];                                                               \
    _Pragma("unroll")                                                          \
    for (int w = 0; w < 9; ++w) {                                              \
      int t = lcol + w - 4;                                                    \
      bf16x8 graw = (t >= 0 && t < LL)                                         \
          ? *(const bf16x8*)(FG + (size_t)(gb + t) * 256 + 128 + u8) : gz;     \
      f32x4 pw0 = *(const f32x4*)(pwP + w * 128 + u8);                         \
      f32x4 pw1 = *(const f32x4*)(pwP + w * 128 + u8 + 4);                     \
      float a = 0.f;                                                           \
      _Pragma("unroll")                                                        \
      for (int c = 0; c < 4; ++c) {                                            \
        float e = exp2f(bf2f((unsigned short)fraw[c]) +                        \
                        bf2f((unsigned short)graw[c]) + pw0[c]);               \
        a = fmaf(vr0[c], __builtin_amdgcn_rcpf(1.f + e), a);                   \
      }                                                                        \
      _Pragma("unroll")                                                        \
      for (int c = 0; c < 4; ++c) {                                            \
        float e = exp2f(bf2f((unsigned short)fraw[4 + c]) +                    \
                        bf2f((unsigned short)graw[4 + c]) + pw1[c]);           \
        a = fmaf(vr1[c], __builtin_amdgcn_rcpf(1.f + e), a);                   \
      }                                                                        \
      a += __shfl_xor(a, 1, 64);                                               \
      a += __shfl_xor(a, 2, 64);                                               \
      a += __shfl_xor(a, 4, 64);                                               \
      a += __shfl_xor(a, 8, 64);                                               \
      sc[w] = a;                                                               \
    }                                                                          \
    float mn = sc[0];                                                          \
    _Pragma("unroll")                                                          \
    for (int w = 1; w < 9; ++w) mn = fminf(mn, sc[w]);                         \
    float pp[9], sum = 0.f;                                                    \
    _Pragma("unroll")                                                          \
    for (int w = 0; w < 9; ++w) { pp[w] = exp2f(TANHK * (mn - sc[w])); sum += pp[w]; } \
    float inv = __builtin_amdgcn_rcpf(sum);                                    \
    if (l15 < 9) {                                                             \
      float wv = pp[0];                                                        \
      _Pragma("unroll")                                                        \
      for (int w = 1; w < 9; ++w) wv = (l15 == w) ? pp[w] : wv;                \
      wtT[l15 * 32768 + row] = wv * inv;                                       \
    }                                                                          \
  }

  if (!(wid & 2)) { DO_SCORE(0); DO_SCORE(1); }
  else            { DO_SCORE(2); DO_SCORE(3); }
#undef DO_SCORE
}

// ---------- K3: out-GEMM; A from E-LDS, B coalesced frags, wt epilogue ----------
__global__ __launch_bounds__(256, 4) void out_kernel(
    const float* __restrict__ emb, const unsigned short* __restrict__ CwFrag,
    const float* __restrict__ wtT, const float* __restrict__ cnn,
    const float* __restrict__ cnnb, float* __restrict__ out) {
  __shared__ uint4 E[48 * 16];
  int tid = threadIdx.x;
  int bid = blockIdx.x;
  int b = bid >> 5, l0 = (bid & 31) << 5;
  int lane = tid & 63, wid = tid >> 6;
  int l15 = lane & 15, l4 = lane >> 4;
  const bf16x8* Cf = (const bf16x8*)CwFrag;

  #pragma unroll
  for (int s = 0; s < 3; ++s) {
    int i = tid + s * 256;
    int er = i >> 4, g = i & 15;
    int t = l0 + er - 4;
    uint4 v = {0u, 0u, 0u, 0u};
    if (er < 40 && t >= 0 && t < LL) {
      const float4* src = (const float4*)(emb + ((size_t)(b * LL + t) << 7) + g * 8);
      float4 x0 = src[0], x1 = src[1];
      v.x = cvt_pk_bf16(x0.x, x0.y);
      v.y = cvt_pk_bf16(x0.z, x0.w);
      v.z = cvt_pk_bf16(x1.x, x1.y);
      v.w = cvt_pk_bf16(x1.z, x1.w);
    }
    E[er * 16 + (g ^ (er & 7))] = v;
  }
  __syncthreads();

  const bf16x8* Eb = (const bf16x8*)E;
  int h0 = (wid << 5) + l15;
  f32x4 fin[2][2];
  #pragma unroll
  for (int m = 0; m < 2; ++m)
    #pragma unroll
    for (int n = 0; n < 2; ++n) fin[m][n] = (f32x4){0.f, 0.f, 0.f, 0.f};
  #pragma unroll
  for (int w = 0; w < 9; ++w) {
    f32x4 tmp[2][2];
    #pragma unroll
    for (int m = 0; m < 2; ++m)
      #pragma unroll
      for (int n = 0; n < 2; ++n) tmp[m][n] = (f32x4){0.f, 0.f, 0.f, 0.f};
    #pragma unroll
    for (int kk = 0; kk < 4; ++kk) {
      int gk = kk * 4 + l4;
      bf16x8 aF[2];
      #pragma unroll
      for (int m = 0; m < 2; ++m) {
        int er = m * 16 + l15 + w;
        aF[m] = Eb[er * 16 + (gk ^ (er & 7))];
      }
      #pragma unroll
      for (int n = 0; n < 2; ++n) {
        bf16x8 bF = Cf[((w * 8 + (wid << 1) + n) * 4 + kk) * 64 + lane];
        #pragma unroll
        for (int m = 0; m < 2; ++m)
          tmp[m][n] = __builtin_amdgcn_mfma_f32_16x16x32_bf16(aF[m], bF, tmp[m][n], 0, 0, 0);
      }
    }
    float cp0 = cnn[(w * 138 + 128) * 128 + h0];
    float cp1 = cnn[(w * 138 + 128) * 128 + h0 + 16];
    #pragma unroll
    for (int m = 0; m < 2; ++m) {
      f32x4 wt4 = *(const f32x4*)(wtT + w * 32768 + (bid << 5) + m * 16 + l4 * 4);
      #pragma unroll
      for (int j = 0; j < 4; ++j) {
        fin[m][0][j] += wt4[j] * (tmp[m][0][j] + cp0);
        fin[m][1][j] += wt4[j] * (tmp[m][1][j] + cp1);
      }
    }
  }
  float cb0 = cnnb[h0], cb1 = cnnb[h0 + 16];
  #pragma unroll
  for (int m = 0; m < 2; ++m)
    #pragma unroll
    for (int j = 0; j < 4; ++j) {
      int r = m * 16 + l4 * 4 + j;
      size_t o = ((size_t)(b * LL + l0 + r) << 7) + h0;
      out[o]      = fin[m][0][j] + cb0;
      out[o + 16] = fin[m][1][j] + cb1;
    }
}

extern "C" void kernel_launch(void* const* d_in, const int* in_sizes, int n_in,
                              void* d_out, int out_size, void* d_ws, size_t ws_size,
                              hipStream_t stream) {
  const float* emb  = (const float*)d_in[0];
  // d_in[1] masks: unused by reference
  const float* w1   = (const float*)d_in[2];
  const float* w1b  = (const float*)d_in[3];
  const float* w2   = (const float*)d_in[4];
  const float* w2b  = (const float*)d_in[5];
  const float* vw   = (const float*)d_in[6];
  // d_in[7] v_b: softmax-invariant, unused
  const float* cnn  = (const float*)d_in[8];
  const float* cnnb = (const float*)d_in[9];
  float* out = (float*)d_out;

  char* ws = (char*)d_ws;
  unsigned short* W12Frag = (unsigned short*)(ws);
  unsigned short* CwFrag  = (unsigned short*)(ws + 65536);
  float* wtT              = (float*)(ws + 360448);
  unsigned short* FG      = (unsigned short*)(ws + 1540096);

  prep_kernel<<<704, 256, 0, stream>>>(w1, w2, cnn, W12Frag, CwFrag);
  fg_kernel<<<2048, 64, 0, stream>>>(emb, W12Frag, FG);
  wt_kernel<<<1024, 256, 0, stream>>>(FG, w1, w1b, w2, w2b, vw, wtT);
  out_kernel<<<1024, 256, 0, stream>>>(emb, CwFrag, wtT, cnn, cnnb, out);
}

// Round 11
// 124.790 us; speedup vs baseline: 1.3369x; 1.3369x over previous
//
#include <hip/hip_runtime.h>
#include <hip/hip_bf16.h>

// B=32 L=1024 D=128 H=128 W=9 F=137. Output f32 (32,1024,128).
// ws: W12Frag bf16[64t][64][8] @0 (64KB); CwFrag bf16[288t][64][8] @65536 (288KB)
// Fragment order (16x16x32 B-frag): tile=(nTile,kk); lane l holds n=nTile*16+(l&15),
// k=kk*32+(l>>4)*8..+8 — wave bf16x8 load = 1KB coalesced.
// mega: 512 blocks x 512 thr (8 waves), 64 rows/block, 2 blocks/CU (halves per-CU
// CwFrag L2 traffic vs 32-row blocks). LDS 49808B:
//   E   @0     uint4[80*16] : emb rows l0-4..l0+67 bf16 (er<72 real), XOR-swz granules
//   GP  @20480 u16[80][136] : K*g PERMUTED h-order p=(h&15)*8+(h>>4), 272B rows
//   pwP @42240 f32[9][128] perm; vwP @46848 f32[128] perm; wtT @47360 f32[9][68]
// f in MFMA accumulators (never LDS): wave t -> f-tile (t&3), J-half (t>>2).
// Phase 4: explicit double-buffered bF prefetch (bufA/bufB) + setprio.
// tanh(x)=1-2*rcp(1+exp2(K*x)), K=2*log2(e); Sum_h vw const cancels in softmax.

typedef __attribute__((ext_vector_type(8))) short bf16x8;
typedef __attribute__((ext_vector_type(4))) float f32x4;

#define LL 1024
#define TANHK 2.885390081777927f

__device__ __forceinline__ unsigned short f2bf(float f) {
  unsigned int u = __float_as_uint(f);
  u = u + 0x7FFFu + ((u >> 16) & 1u);   // RNE
  return (unsigned short)(u >> 16);
}
__device__ __forceinline__ float bf2f(unsigned short us) {
  return __uint_as_float(((unsigned int)us) << 16);
}
__device__ __forceinline__ unsigned cvt_pk_bf16(float lo, float hi) {
  unsigned r;
  asm("v_cvt_pk_bf16_f32 %0, %1, %2" : "=v"(r) : "v"(lo), "v"(hi));
  return r;
}

// ---------- prep: fragment-ordered bf16 weight copies (proven R6) ----------
__global__ __launch_bounds__(256) void prep_kernel(
    const float* __restrict__ w1, const float* __restrict__ w2,
    const float* __restrict__ cnn,
    unsigned short* __restrict__ W12Frag, unsigned short* __restrict__ CwFrag) {
  int gid = blockIdx.x * 256 + threadIdx.x;
  if (blockIdx.x < 128) {            // 32768: W12Frag
    int d = gid >> 8, n = gid & 255;
    float v = (n < 128) ? w1[d * 128 + n] : w2[d * 128 + (n - 128)];
    int tile = (n >> 4) * 4 + (d >> 5);
    int lane = ((d >> 3) & 3) * 16 + (n & 15);
    W12Frag[(tile * 64 + lane) * 8 + (d & 7)] = f2bf(v);
  } else {                           // 147456: CwFrag
    int idx = gid - 32768;
    int h = idx & 127;
    int wd = idx >> 7;
    int w = wd >> 7, d = wd & 127;
    float v = cnn[(w * 137 + d) * 128 + h];
    int tile = (w * 8 + (h >> 4)) * 4 + (d >> 5);
    int lane = ((d >> 3) & 3) * 16 + (h & 15);
    CwFrag[(tile * 64 + lane) * 8 + (d & 7)] = f2bf(v);
  }
}

// ---------- mega ----------
__global__ __launch_bounds__(512, 4) void mega_kernel(
    const float* __restrict__ emb,
    const unsigned short* __restrict__ W12Frag,
    const unsigned short* __restrict__ CwFrag,
    const float* __restrict__ w1, const float* __restrict__ w1b,
    const float* __restrict__ w2, const float* __restrict__ w2b,
    const float* __restrict__ vw,
    const float* __restrict__ cnn, const float* __restrict__ cnnb,
    float* __restrict__ out) {
  extern __shared__ __align__(16) unsigned char smem[];
  uint4* E           = (uint4*)smem;                        // 20480
  unsigned short* GP = (unsigned short*)(smem + 20480);     // 21760
  float* pwP         = (float*)(smem + 42240);              // 4608
  float* vwP         = (float*)(smem + 46848);              // 512
  float* wtT         = (float*)(smem + 47360);              // 2448 -> 49808

  int tid = threadIdx.x;
  int bid = blockIdx.x;
  int b = bid >> 4, l0 = (bid & 15) << 6;
  int lane = tid & 63, wid = tid >> 6;
  int l15 = lane & 15, l4 = lane >> 4;
  const bf16x8* Wf = (const bf16x8*)W12Frag;
  const bf16x8* Cf = (const bf16x8*)CwFrag;

  // ---- phase 0: stage E (80 rows: 72 real + 8 pad) + permuted pwP/vwP ----
  #pragma unroll
  for (int s = 0; s < 5; ++s) {
    int i = tid + s * 512;
    if (i < 1280) {
      int er = i >> 4, g = i & 15;
      int t = l0 + er - 4;
      uint4 v = {0u, 0u, 0u, 0u};
      if (er < 72 && t >= 0 && t < LL) {
        const float4* src = (const float4*)(emb + ((size_t)(b * LL + t) << 7) + g * 8);
        float4 x0 = src[0], x1 = src[1];
        v.x = cvt_pk_bf16(x0.x, x0.y);
        v.y = cvt_pk_bf16(x0.z, x0.w);
        v.z = cvt_pk_bf16(x1.x, x1.y);
        v.w = cvt_pk_bf16(x1.z, x1.w);
      }
      E[er * 16 + (g ^ (er & 7))] = v;
    } else if (i < 2432) {
      int idx = i - 1280;
      int w = idx >> 7, p = idx & 127;
      int h = ((p & 7) << 4) + (p >> 3);      // permuted order
      pwP[idx] = TANHK * (w2[(128 + w) * 128 + h] + w2b[h] +
                          w1[132 * 128 + h] + w1b[h]);
    } else {
      int p = i - 2432;
      int h = ((p & 7) << 4) + (p >> 3);
      vwP[p] = vw[h];
    }
  }
  __syncthreads();

  // ---- phase 2: f-tile per wave (regs, tile wid&3) + 5 g-tiles -> GP ----
  const bf16x8* Eb = (const bf16x8*)E;
  f32x4 af[8];
  #pragma unroll
  for (int nn = 0; nn < 8; ++nn) af[nn] = (f32x4){0.f, 0.f, 0.f, 0.f};
  {
    int er0f = 4 + ((wid & 3) << 4);
    __builtin_amdgcn_s_setprio(1);
    #pragma unroll
    for (int kk = 0; kk < 4; ++kk) {
      int gk = kk * 4 + l4;
      int er = er0f + l15;
      bf16x8 aF = Eb[er * 16 + (gk ^ (er & 7))];
      #pragma unroll
      for (int nn = 0; nn < 8; ++nn) {
        bf16x8 bF = Wf[(nn * 4 + kk) * 64 + lane];
        af[nn] = __builtin_amdgcn_mfma_f32_16x16x32_bf16(aF, bF, af[nn], 0, 0, 0);
      }
    }
    __builtin_amdgcn_s_setprio(0);
  }
  if (wid < 5) {
    int er0g = wid << 4;
    f32x4 ag[8];
    #pragma unroll
    for (int nn = 0; nn < 8; ++nn) ag[nn] = (f32x4){0.f, 0.f, 0.f, 0.f};
    __builtin_amdgcn_s_setprio(1);
    #pragma unroll
    for (int kk = 0; kk < 4; ++kk) {
      int gk = kk * 4 + l4;
      int er = er0g + l15;
      bf16x8 aF = Eb[er * 16 + (gk ^ (er & 7))];
      #pragma unroll
      for (int nn = 0; nn < 8; ++nn) {
        bf16x8 bF = Wf[((8 + nn) * 4 + kk) * 64 + lane];
        ag[nn] = __builtin_amdgcn_mfma_f32_16x16x32_bf16(aF, bF, ag[nn], 0, 0, 0);
      }
    }
    __builtin_amdgcn_s_setprio(0);
    #pragma unroll
    for (int j = 0; j < 4; ++j) {           // K-prescaled, permuted, b128 writes
      int row = er0g + l4 * 4 + j;
      uint4 v;
      v.x = cvt_pk_bf16(TANHK * ag[0][j], TANHK * ag[1][j]);
      v.y = cvt_pk_bf16(TANHK * ag[2][j], TANHK * ag[3][j]);
      v.z = cvt_pk_bf16(TANHK * ag[4][j], TANHK * ag[5][j]);
      v.w = cvt_pk_bf16(TANHK * ag[6][j], TANHK * ag[7][j]);
      *(uint4*)(GP + row * 136 + l15 * 8) = v;
    }
  }
  __syncthreads();

  // ---- phase 3: scores + softmax; f from af[] regs, g/pw/vw permuted ----
  {
    int rbase = (wid & 3) << 4;
    int u8 = l15 * 8;
    f32x4 vr0 = *(const f32x4*)(vwP + u8);
    f32x4 vr1 = *(const f32x4*)(vwP + u8 + 4);

#define DO_SCORE(J)                                                            \
    {                                                                          \
      int rl = rbase + l4 * 4 + (J);                                           \
      float sc[9];                                                             \
      _Pragma("unroll")                                                        \
      for (int w = 0; w < 9; ++w) {                                            \
        bf16x8 graw = *(const bf16x8*)(GP + (rl + w) * 136 + u8);              \
        f32x4 pw0 = *(const f32x4*)(pwP + w * 128 + u8);                       \
        f32x4 pw1 = *(const f32x4*)(pwP + w * 128 + u8 + 4);                   \
        float a = 0.f;                                                         \
        _Pragma("unroll")                                                      \
        for (int c = 0; c < 4; ++c) {                                          \
          float e = exp2f(fmaf(af[c][(J)], TANHK,                              \
                               bf2f((unsigned short)graw[c]) + pw0[c]));       \
          a = fmaf(vr0[c], __builtin_amdgcn_rcpf(1.f + e), a);                 \
        }                                                                      \
        _Pragma("unroll")                                                      \
        for (int c = 0; c < 4; ++c) {                                          \
          float e = exp2f(fmaf(af[4 + c][(J)], TANHK,                          \
                               bf2f((unsigned short)graw[4 + c]) + pw1[c]));   \
          a = fmaf(vr1[c], __builtin_amdgcn_rcpf(1.f + e), a);                 \
        }                                                                      \
        a += __shfl_xor(a, 1, 64);                                             \
        a += __shfl_xor(a, 2, 64);                                             \
        a += __shfl_xor(a, 4, 64);                                             \
        a += __shfl_xor(a, 8, 64);                                             \
        sc[w] = a;                                                             \
      }                                                                        \
      float mn = sc[0];                                                        \
      _Pragma("unroll")                                                        \
      for (int w = 1; w < 9; ++w) mn = fminf(mn, sc[w]);                       \
      float pp[9], sum = 0.f;                                                  \
      _Pragma("unroll")                                                        \
      for (int w = 0; w < 9; ++w) { pp[w] = exp2f(TANHK * (mn - sc[w])); sum += pp[w]; } \
      float inv = __builtin_amdgcn_rcpf(sum);                                  \
      if (l15 < 9) {                                                           \
        float wv = pp[0];                                                      \
        _Pragma("unroll")                                                      \
        for (int w = 1; w < 9; ++w) wv = (l15 == w) ? pp[w] : wv;              \
        wtT[l15 * 68 + rl] = wv * inv;                                         \
      }                                                                        \
    }

    if (!(wid & 4)) { DO_SCORE(0); DO_SCORE(1); }
    else            { DO_SCORE(2); DO_SCORE(3); }
#undef DO_SCORE
  }
  __syncthreads();

  // ---- phase 4: out-GEMM; A from E, bF double-buffer prefetch, wt epilogue ----
  int wr = wid >> 2, wc = wid & 3;      // wave tile: 32 rows x 32 h
  int h0 = (wc << 5) + l15;
  f32x4 fin00 = {0.f,0.f,0.f,0.f}, fin01 = {0.f,0.f,0.f,0.f};
  f32x4 fin10 = {0.f,0.f,0.f,0.f}, fin11 = {0.f,0.f,0.f,0.f};
  bf16x8 bufA[4][2], bufB[4][2];

#define LOADB(BUF, W)                                                          \
  _Pragma("unroll")                                                            \
  for (int kk = 0; kk < 4; ++kk)                                               \
    _Pragma("unroll")                                                          \
    for (int n = 0; n < 2; ++n)                                                \
      BUF[kk][n] = Cf[(((W) * 8 + (wc << 1) + n) * 4 + kk) * 64 + lane];

#define STEP(W, CUR, NXT)                                                      \
  {                                                                            \
    if ((W) < 8) { LOADB(NXT, (W) + 1); }                                      \
    f32x4 t00 = {0.f,0.f,0.f,0.f}, t01 = {0.f,0.f,0.f,0.f};                    \
    f32x4 t10 = {0.f,0.f,0.f,0.f}, t11 = {0.f,0.f,0.f,0.f};                    \
    __builtin_amdgcn_s_setprio(1);                                             \
    _Pragma("unroll")                                                          \
    for (int kk = 0; kk < 4; ++kk) {                                           \
      int gk = kk * 4 + l4;                                                    \
      int er0 = wr * 32 + l15 + (W);                                           \
      int er1 = er0 + 16;                                                      \
      bf16x8 a0 = Eb[er0 * 16 + (gk ^ (er0 & 7))];                             \
      bf16x8 a1 = Eb[er1 * 16 + (gk ^ (er1 & 7))];                             \
      t00 = __builtin_amdgcn_mfma_f32_16x16x32_bf16(a0, CUR[kk][0], t00, 0, 0, 0); \
      t10 = __builtin_amdgcn_mfma_f32_16x16x32_bf16(a1, CUR[kk][0], t10, 0, 0, 0); \
      t01 = __builtin_amdgcn_mfma_f32_16x16x32_bf16(a0, CUR[kk][1], t01, 0, 0, 0); \
      t11 = __builtin_amdgcn_mfma_f32_16x16x32_bf16(a1, CUR[kk][1], t11, 0, 0, 0); \
    }                                                                          \
    __builtin_amdgcn_s_setprio(0);                                             \
    float cp0 = cnn[((W) * 138 + 128) * 128 + h0];                             \
    float cp1 = cnn[((W) * 138 + 128) * 128 + h0 + 16];                        \
    f32x4 wa = *(const f32x4*)(wtT + (W) * 68 + wr * 32 + l4 * 4);             \
    f32x4 wb = *(const f32x4*)(wtT + (W) * 68 + wr * 32 + 16 + l4 * 4);        \
    _Pragma("unroll")                                                          \
    for (int j = 0; j < 4; ++j) {                                              \
      fin00[j] += wa[j] * (t00[j] + cp0);                                      \
      fin01[j] += wa[j] * (t01[j] + cp1);                                      \
      fin10[j] += wb[j] * (t10[j] + cp0);                                      \
      fin11[j] += wb[j] * (t11[j] + cp1);                                      \
    }                                                                          \
  }

  LOADB(bufA, 0);
  STEP(0, bufA, bufB); STEP(1, bufB, bufA); STEP(2, bufA, bufB);
  STEP(3, bufB, bufA); STEP(4, bufA, bufB); STEP(5, bufB, bufA);
  STEP(6, bufA, bufB); STEP(7, bufB, bufA); STEP(8, bufA, bufB);
#undef STEP
#undef LOADB

  float cb0 = cnnb[h0], cb1 = cnnb[h0 + 16];
  #pragma unroll
  for (int j = 0; j < 4; ++j) {
    int r0 = wr * 32 + l4 * 4 + j;
    size_t o0 = ((size_t)(b * LL + l0 + r0) << 7) + h0;
    out[o0]      = fin00[j] + cb0;
    out[o0 + 16] = fin01[j] + cb1;
    size_t o1 = ((size_t)(b * LL + l0 + r0 + 16) << 7) + h0;
    out[o1]      = fin10[j] + cb0;
    out[o1 + 16] = fin11[j] + cb1;
  }
}

extern "C" void kernel_launch(void* const* d_in, const int* in_sizes, int n_in,
                              void* d_out, int out_size, void* d_ws, size_t ws_size,
                              hipStream_t stream) {
  const float* emb  = (const float*)d_in[0];
  // d_in[1] masks: unused by reference
  const float* w1   = (const float*)d_in[2];
  const float* w1b  = (const float*)d_in[3];
  const float* w2   = (const float*)d_in[4];
  const float* w2b  = (const float*)d_in[5];
  const float* vw   = (const float*)d_in[6];
  // d_in[7] v_b: softmax-invariant, unused
  const float* cnn  = (const float*)d_in[8];
  const float* cnnb = (const float*)d_in[9];
  float* out = (float*)d_out;

  char* ws = (char*)d_ws;
  unsigned short* W12Frag = (unsigned short*)(ws);
  unsigned short* CwFrag  = (unsigned short*)(ws + 65536);

  prep_kernel<<<704, 256, 0, stream>>>(w1, w2, cnn, W12Frag, CwFrag);
  mega_kernel<<<512, 512, 49808, stream>>>(emb, W12Frag, CwFrag, w1, w1b, w2, w2b,
                                           vw, cnn, cnnb, out);
}